// Round 13
// baseline (504.651 us; speedup 1.0000x reference)
//
#include <hip/hip_runtime.h>

// V=50000, E=64, B=64, T=1024, F=128, H=128, WIN=3, PAD=1

typedef __attribute__((ext_vector_type(8))) unsigned short ushort8;
typedef __attribute__((ext_vector_type(8))) short bf16x8;
typedef __attribute__((ext_vector_type(4))) float f32x4;

__device__ __forceinline__ unsigned short f2bf(float f) {
  unsigned int u = __float_as_uint(f);
  u += 0x7fffu + ((u >> 16) & 1u);   // RNE
  return (unsigned short)(u >> 16);
}
__device__ __forceinline__ float bf2f(unsigned short us) {
  return __uint_as_float(((unsigned int)us) << 16);
}
#if __has_builtin(__builtin_amdgcn_sdot4)
#define SDOT4(a, b, c) __builtin_amdgcn_sdot4((int)(a), (int)(b), (c), false)
#else
__device__ __forceinline__ int sdot4_sw(int a, int b, int c) {
#pragma unroll
  for (int i = 0; i < 4; ++i)
    c += ((a << (24 - 8 * i)) >> 24) * ((b << (24 - 8 * i)) >> 24);
  return c;
}
#define SDOT4(a, b, c) sdot4_sw((int)(a), (int)(b), (c))
#endif
// DPP quad_perm lane exchanges
#define DPP_X1(x) __builtin_amdgcn_update_dpp(0, (x), 0xB1, 0xF, 0xF, true)  // xor 1
#define DPP_X2(x) __builtin_amdgcn_update_dpp(0, (x), 0x4E, 0xF, 0xF, true)  // xor 2

#if __has_builtin(__builtin_amdgcn_rcpf)
#define FRCP(x) __builtin_amdgcn_rcpf(x)
#else
#define FRCP(x) (1.0f / (x))
#endif

// Eigen ptanh_float rational approximation: err ~1e-7 on the clamped range.
// One v_rcp on the dependency path instead of exp+rcp chains.
__device__ __forceinline__ float fast_tanh(float y) {
  y = fminf(fmaxf(y, -7.90531110763549f), 7.90531110763549f);
  const float y2 = y * y;
  float p = fmaf(y2, -2.76076847742355e-16f, 2.00018790482477e-13f);
  p = fmaf(y2, p, -8.60467152213735e-11f);
  p = fmaf(y2, p, 5.12229709037114e-08f);
  p = fmaf(y2, p, 1.48572235717979e-05f);
  p = fmaf(y2, p, 6.37261928875436e-04f);
  p = fmaf(y2, p, 4.89352455891786e-03f);
  p = y * p;
  float q = fmaf(y2, 1.19825839466702e-06f, 1.18534705686654e-04f);
  q = fmaf(y2, q, 2.26843463243900e-03f);
  q = fmaf(y2, q, 4.89352518554385e-03f);
  return p * FRCP(q);
}
__device__ __forceinline__ float fast_sigmoid(float x) {
  return fmaf(fast_tanh(0.5f * x), 0.5f, 0.5f);
}

// ---------------------------------------------------------------------------
// K0: CWb[g][k] = bf16( sum_f Wih[g][f]*conv_w[f][k] );
//     xbias[g] = b_ih[g] + Wih[g]·conv_b (+ b_hh folded for r,z gates).
__global__ void k0_fuse(const float* __restrict__ conv_w, const float* __restrict__ conv_b,
                        const float* __restrict__ w_ih_f, const float* __restrict__ b_ih_f,
                        const float* __restrict__ w_ih_b, const float* __restrict__ b_ih_b,
                        const float* __restrict__ b_hh_f, const float* __restrict__ b_hh_b,
                        unsigned short* __restrict__ CWb, float* __restrict__ xbias) {
  int flat = blockIdx.x * 256 + threadIdx.x;
  if (flat >= 768 * 192) return;
  int g = flat / 192, k = flat % 192;
  const float* wih = (g < 384) ? w_ih_f : w_ih_b;
  int gg = (g < 384) ? g : g - 384;
  float acc = 0.f;
  for (int f = 0; f < 128; ++f) acc += wih[gg * 128 + f] * conv_w[f * 192 + k];
  CWb[g * 192 + k] = f2bf(acc);
  if (k == 0) {
    const float* bih = (g < 384) ? b_ih_f : b_ih_b;
    const float* bhh = (g < 384) ? b_hh_f : b_hh_b;
    float bb = bih[gg];
    if (gg < 256) bb += bhh[gg];   // fold hidden bias for r,z
    for (int f = 0; f < 128; ++f) bb += wih[gg * 128 + f] * conv_b[f];
    xbias[g] = bb;
  }
}

// ---------------------------------------------------------------------------
// K0b: per-row i8 quantization of W_hh (both dirs): row R = dir*384+gate*128+j.
__global__ void k0b_quant(const float* __restrict__ w_hh_f, const float* __restrict__ w_hh_b,
                          unsigned int* __restrict__ Wq8, float* __restrict__ ws) {
  int tid = blockIdx.x * 256 + threadIdx.x;
  int R = tid >> 5, dw = tid & 31;
  if (R >= 768) return;
  int dir = R / 384, rr = R - dir * 384;
  const float* w = (dir ? w_hh_b : w_hh_f) + (size_t)rr * 128 + dw * 4;
  float4 v = *reinterpret_cast<const float4*>(w);
  float am = fmaxf(fmaxf(fabsf(v.x), fabsf(v.y)), fmaxf(fabsf(v.z), fabsf(v.w)));
#pragma unroll
  for (int m = 1; m < 32; m <<= 1) am = fmaxf(am, __shfl_xor(am, m));
  float inv = (am > 0.f) ? 127.f / am : 0.f;
  int q0 = (int)rintf(v.x * inv), q1 = (int)rintf(v.y * inv);
  int q2 = (int)rintf(v.z * inv), q3 = (int)rintf(v.w * inv);
  unsigned int pk = (q0 & 255) | ((q1 & 255) << 8) | ((q2 & 255) << 16) | ((q3 & 255) << 24);
  Wq8[R * 32 + dw] = pk;
  if (dw == 0) ws[R] = am / 16129.f;
}

// ---------------------------------------------------------------------------
// K1: xp[b][t][g] = bf16( xbias[g] + sum_k A[t][k]*CW[g][k] ) via MFMA bf16.
__global__ __launch_bounds__(256) void k1_gemm(const int* __restrict__ ipts,
                                               const float* __restrict__ emb,
                                               const unsigned short* __restrict__ CWb,
                                               const float* __restrict__ xbias,
                                               unsigned short* __restrict__ xp) {
  __shared__ __align__(16) unsigned short xs[130][72];
  __shared__ __align__(16) unsigned short wsb[128][200];
  const int bid = blockIdx.x;
  const int gb = bid % 6, tb = bid / 6;
  const int b = tb >> 3, t0 = (tb & 7) << 7, g0 = gb << 7;
  const int tid = threadIdx.x;

  for (int c = tid; c < 130 * 16; c += 256) {
    int row = c >> 4, cc = c & 15;
    int t = t0 - 1 + row;
    float4 v = make_float4(0.f, 0.f, 0.f, 0.f);
    if (t >= 0 && t < 1024) {
      int tok = ipts[b * 1024 + t];
      v = *reinterpret_cast<const float4*>(emb + (size_t)tok * 64 + cc * 4);
    }
    ushort4 pv;
    pv.x = f2bf(v.x); pv.y = f2bf(v.y); pv.z = f2bf(v.z); pv.w = f2bf(v.w);
    *reinterpret_cast<ushort4*>(&xs[row][cc * 4]) = pv;
  }
  for (int c = tid; c < 128 * 24; c += 256) {
    int g = c / 24, cc = c % 24;
    *reinterpret_cast<ushort8*>(&wsb[g][cc * 8]) =
        *reinterpret_cast<const ushort8*>(CWb + (size_t)(g0 + g) * 192 + cc * 8);
  }
  __syncthreads();

  const int lane = tid & 63, wid = tid >> 6;
  const int wy = wid >> 1, wx = wid & 1;
  const int ln15 = lane & 15, lhi = lane >> 4;

  f32x4 acc[4][4];
#pragma unroll
  for (int i = 0; i < 4; ++i)
#pragma unroll
    for (int j = 0; j < 4; ++j) acc[i][j] = (f32x4){0.f, 0.f, 0.f, 0.f};

#pragma unroll
  for (int kk = 0; kk < 6; ++kk) {
    const int w = kk >> 1;
    const int e0 = (kk & 1) * 32 + lhi * 8;
    const int k0 = kk * 32 + lhi * 8;
    bf16x8 a[4], bb[4];
#pragma unroll
    for (int i = 0; i < 4; ++i)
      a[i] = *reinterpret_cast<const bf16x8*>(&xs[wy * 64 + i * 16 + ln15 + w][e0]);
#pragma unroll
    for (int j = 0; j < 4; ++j)
      bb[j] = *reinterpret_cast<const bf16x8*>(&wsb[wx * 64 + j * 16 + ln15][k0]);
#pragma unroll
    for (int i = 0; i < 4; ++i)
#pragma unroll
      for (int j = 0; j < 4; ++j)
        acc[i][j] = __builtin_amdgcn_mfma_f32_16x16x32_bf16(a[i], bb[j], acc[i][j], 0, 0, 0);
  }

  float bias[4];
#pragma unroll
  for (int j = 0; j < 4; ++j) bias[j] = xbias[g0 + wx * 64 + j * 16 + ln15];

  unsigned short* outp = xp + (size_t)(b * 1024 + t0 + wy * 64) * 768 + g0 + wx * 64;
#pragma unroll
  for (int i = 0; i < 4; ++i)
#pragma unroll
    for (int r = 0; r < 4; ++r) {
      int m = i * 16 + lhi * 4 + r;
#pragma unroll
      for (int j = 0; j < 4; ++j)
        outp[(size_t)m * 768 + j * 16 + ln15] = f2bf(acc[i][j][r] + bias[j]);
    }
}

// ---------------------------------------------------------------------------
// K2: GRU scan — one block (256 thr = 4 waves) per (batch, direction).
//     Lane tid owns (row = tid>>1, k-half = tid&1): 3 gate half-dots x 64 k
//     = 48 sdot4/lane; DPP xor1 completes each dot in both pair lanes.
//     GATES: polynomial tanh (Eigen ptanh; 1 v_rcp on path) replaces the
//     exp/rcp transcendental chain — the dominant serial-latency component
//     (R12 model: ~310 issue + ~620 stall; trans chain ~300 of the stall).
//     h-publish: DPP xor2 packs the pair rows' bytes -> 64 ds_write_b16
//     (2-way dword alias, free) instead of 128 b8 (4-way serialize).
//     h double-buffered in LDS; ONE raw s_barrier + lgkmcnt(0) per step.
//     x: 3 global_load_ushort asm loads/lane, depth-2 ring, counted vmcnt(3).
__global__ __launch_bounds__(256, 1) void k2_scan(
    const int* __restrict__ seqlen, const float* __restrict__ hidden,
    const float* __restrict__ b_hh_f, const float* __restrict__ b_hh_b,
    const unsigned int* __restrict__ Wq8, const float* __restrict__ ws,
    const unsigned short* __restrict__ xp, float* __restrict__ mot) {
  __shared__ __align__(16) unsigned int hq[2][32];   // h as i8, double-buffered
  const int tid = threadIdx.x;
  const int b = blockIdx.x & 63, dir = blockIdx.x >> 6;
  const int row = tid >> 1;      // output row 0..127
  const int half = tid & 1;      // k-half
  const float* bhh = dir ? b_hh_b : b_hh_f;

  // --- W_hh i8: 3 gates x my 64-k half = 12 dwordx4 via volatile asm ---
  uint4 Wq[3][4];
#pragma unroll
  for (int g = 0; g < 3; ++g) {
    const uint4* rp = reinterpret_cast<const uint4*>(
        Wq8 + (size_t)(dir * 384 + g * 128 + row) * 32 + half * 16);
#pragma unroll
    for (int c = 0; c < 4; ++c)
      asm volatile("global_load_dwordx4 %0, %1, off"
                   : "=v"(Wq[g][c]) : "v"(rp + c) : "memory");
  }
  asm volatile("s_waitcnt vmcnt(0)" ::: "memory");
  __builtin_amdgcn_sched_barrier(0);

  const float sc0 = ws[dir * 384 + row];
  const float sc1 = ws[dir * 384 + 128 + row];
  const float sc2 = ws[dir * 384 + 256 + row];
  const float bh2 = bhh[256 + row];

  const int len = seqlen[b];
  float h = hidden[(size_t)(dir * 64 + b) * 128 + row];
  float acc = 0.f;
  if (!half) {
    int q = (int)rintf(h * 127.f) & 255;
    reinterpret_cast<unsigned char*>(&hq[0][0])[row] = (unsigned char)q;
  }

  // --- x-prefetch ring, depth 2 (slot A = even t, slot B = odd t) ---
  const unsigned short* xpb = xp + (size_t)b * (1024 * 768) + dir * 384 + row;
  unsigned int xa0, xa1, xa2, xb0, xb1, xb2;
  int row2;
  {
    const int r0 = dir ? (len - 1) : 0;
    const int r1 = dir ? (len - 2) : 1;            // len >= 256
    const unsigned short* q0 = xpb + (size_t)r0 * 768;
    const unsigned short* q1 = xpb + (size_t)r1 * 768;
    asm volatile("global_load_ushort %0, %1, off"            : "=v"(xa0) : "v"(q0) : "memory");
    asm volatile("global_load_ushort %0, %1, off offset:256" : "=v"(xa1) : "v"(q0) : "memory");
    asm volatile("global_load_ushort %0, %1, off offset:512" : "=v"(xa2) : "v"(q0) : "memory");
    asm volatile("global_load_ushort %0, %1, off"            : "=v"(xb0) : "v"(q1) : "memory");
    asm volatile("global_load_ushort %0, %1, off offset:256" : "=v"(xb1) : "v"(q1) : "memory");
    asm volatile("global_load_ushort %0, %1, off offset:512" : "=v"(xb2) : "v"(q1) : "memory");
    row2 = dir ? (len - 3 >= 0 ? len - 3 : 0) : (2 < len ? 2 : len - 1);
  }
  asm volatile("s_waitcnt lgkmcnt(0)" ::: "memory");
  __builtin_amdgcn_s_barrier();
  __builtin_amdgcn_sched_barrier(0);

#define K2_STEP(T_, CUR_, X0_, X1_, X2_)                                              \
  {                                                                                   \
    asm volatile("s_waitcnt vmcnt(3)" ::: "memory");                                  \
    __builtin_amdgcn_sched_barrier(0);                                                \
    const float xr = bf2f((unsigned short)(X0_));                                     \
    const float xz = bf2f((unsigned short)(X1_));                                     \
    const float xn = bf2f((unsigned short)(X2_));                                     \
    {                                                                                 \
      const unsigned short* pp = xpb + (size_t)row2 * 768;                            \
      asm volatile("global_load_ushort %0, %1, off"            : "=v"(X0_) : "v"(pp) : "memory"); \
      asm volatile("global_load_ushort %0, %1, off offset:256" : "=v"(X1_) : "v"(pp) : "memory"); \
      asm volatile("global_load_ushort %0, %1, off offset:512" : "=v"(X2_) : "v"(pp) : "memory"); \
      row2 = dir ? (row2 > 0 ? row2 - 1 : 0) : (row2 + 1 < len ? row2 + 1 : len - 1); \
    }                                                                                 \
    int ar = 0, az = 0, an = 0;                                                       \
    _Pragma("unroll")                                                                 \
    for (int c = 0; c < 4; ++c) {                                                     \
      const uint4 hv = *reinterpret_cast<const uint4*>(&hq[CUR_][half * 16 + c * 4]); \
      ar = SDOT4(Wq[0][c].x, hv.x, ar); ar = SDOT4(Wq[0][c].y, hv.y, ar);             \
      ar = SDOT4(Wq[0][c].z, hv.z, ar); ar = SDOT4(Wq[0][c].w, hv.w, ar);             \
      az = SDOT4(Wq[1][c].x, hv.x, az); az = SDOT4(Wq[1][c].y, hv.y, az);             \
      az = SDOT4(Wq[1][c].z, hv.z, az); az = SDOT4(Wq[1][c].w, hv.w, az);             \
      an = SDOT4(Wq[2][c].x, hv.x, an); an = SDOT4(Wq[2][c].y, hv.y, an);             \
      an = SDOT4(Wq[2][c].z, hv.z, an); an = SDOT4(Wq[2][c].w, hv.w, an);             \
    }                                                                                 \
    ar += DPP_X1(ar); az += DPP_X1(az); an += DPP_X1(an);                             \
    const float rr = fast_sigmoid(fmaf(sc0, (float)ar, xr));                          \
    const float zz = fast_sigmoid(fmaf(sc1, (float)az, xz));                          \
    const float na = fmaf(rr, fmaf(sc2, (float)an, bh2), xn);                         \
    const float nn = fast_tanh(na);                                                   \
    const float hnew = fmaf(zz, h - nn, nn);                                          \
    if ((T_) < len) {                                                                 \
      h = hnew; acc += hnew;                                                          \
      int q8 = (int)rintf(hnew * 127.f) & 255;                                        \
      int qp = DPP_X2(q8);                                                            \
      if ((tid & 3) == 0)                                                             \
        reinterpret_cast<unsigned short*>(&hq[(CUR_) ^ 1][0])[tid >> 2] =             \
            (unsigned short)(q8 | (qp << 8));                                         \
    }                                                                                 \
    asm volatile("s_waitcnt lgkmcnt(0)" ::: "memory");                                \
    __builtin_amdgcn_s_barrier();                                                     \
    __builtin_amdgcn_sched_barrier(0);                                                \
  }

  const int len2 = (len + 1) & ~1;
  for (int t = 0; t < len2; t += 2) {
    K2_STEP(t, 0, xa0, xa1, xa2);
    K2_STEP(t + 1, 1, xb0, xb1, xb2);
  }
#undef K2_STEP

  if (!half) mot[(size_t)b * 256 + dir * 128 + row] = acc / (float)len;
}

// ---------------------------------------------------------------------------
// K3: out[b] = sigmoid(dot(mot[b], lin_w) + lin_b)
__global__ void k3_final(const float* __restrict__ mot, const float* __restrict__ lin_w,
                         const float* __restrict__ lin_b, float* __restrict__ out) {
  int tid = threadIdx.x;
  int b = tid >> 2, part = tid & 3;
  float s = 0.f;
  for (int i = 0; i < 64; ++i) s += mot[b * 256 + part * 64 + i] * lin_w[part * 64 + i];
  s += __shfl_xor(s, 1);
  s += __shfl_xor(s, 2);
  if (part == 0) out[b] = 1.f / (1.f + __expf(-(s + lin_b[0])));
}

// ---------------------------------------------------------------------------
extern "C" void kernel_launch(void* const* d_in, const int* in_sizes, int n_in,
                              void* d_out, int out_size, void* d_ws, size_t ws_size,
                              hipStream_t stream) {
  const int*   ipts    = (const int*)d_in[0];
  const int*   seqlen  = (const int*)d_in[1];
  const float* hidden  = (const float*)d_in[2];
  const float* emb     = (const float*)d_in[3];
  const float* conv_w  = (const float*)d_in[4];
  const float* conv_b  = (const float*)d_in[5];
  const float* w_ih_f  = (const float*)d_in[6];
  const float* w_hh_f  = (const float*)d_in[7];
  const float* b_ih_f  = (const float*)d_in[8];
  const float* b_hh_f  = (const float*)d_in[9];
  const float* w_ih_b  = (const float*)d_in[10];
  const float* w_hh_b  = (const float*)d_in[11];
  const float* b_ih_b  = (const float*)d_in[12];
  const float* b_hh_b  = (const float*)d_in[13];
  const float* lin_w   = (const float*)d_in[14];
  const float* lin_b   = (const float*)d_in[15];

  char* ws_ = (char*)d_ws;
  unsigned short* CWb = (unsigned short*)(ws_);            // 294,912 B
  float* xbias = (float*)(ws_ + 294912);                   // 3,072 B
  float* mot   = (float*)(ws_ + 298240);                   // 65,536 B
  unsigned int* Wq8 = (unsigned int*)(ws_ + 363776);       // 98,304 B
  float* wsc   = (float*)(ws_ + 462080);                   // 3,072 B
  unsigned short* xp = (unsigned short*)(ws_ + 1048576);   // 100,663,296 B (bf16)
  float* out = (float*)d_out;

  hipLaunchKernelGGL(k0_fuse, dim3(576), dim3(256), 0, stream,
                     conv_w, conv_b, w_ih_f, b_ih_f, w_ih_b, b_ih_b, b_hh_f, b_hh_b,
                     CWb, xbias);
  hipLaunchKernelGGL(k0b_quant, dim3(96), dim3(256), 0, stream,
                     w_hh_f, w_hh_b, Wq8, wsc);
  hipLaunchKernelGGL(k1_gemm, dim3(3072), dim3(256), 0, stream,
                     ipts, emb, CWb, xbias, xp);
  hipLaunchKernelGGL(k2_scan, dim3(128), dim3(256), 0, stream,
                     seqlen, hidden, b_hh_f, b_hh_b, Wq8, wsc, xp, mot);
  hipLaunchKernelGGL(k3_final, dim3(1), dim3(256), 0, stream, mot, lin_w, lin_b, out);
}